// Round 8
// baseline (419.773 us; speedup 1.0000x reference)
//
#include <hip/hip_runtime.h>

// ---------------------------------------------------------------------------
// HAN link-prediction forward. fp16 MFMA GEMMs + fp16 intermediates,
// fp32 alpha tables / accumulation / output.
//   - _group with one metapath == identity (k*W/k*b/q* are dead params)
//   - concatenated 2N-segment CSR (one build serves both directions+layers)
//   - DIRECTION-MAJOR degree sort (128 buckets), consumed descending (LPT)
//   - FUSED agg1 + layer-2 projection (agg_proj_dual); grid 2x768 so ~6
//     blocks/CU are resident (r7 ran 4.9/CU, occupancy 47% = grid-limited)
//   - CSR chain consolidated 9 -> 6 dispatches: deg-hist folded into
//     scan_blk, dual scan_sums in one dispatch, scan_add+deg_scatter fused
//   - agg: masked unroll-4, 16B f16x8 gathers (byte-bound at ~3.9 TB/s)
//   - GEMM1: one-shot 64-row x 64-col blocks, 33.8 KiB LDS, ONE barrier
// ---------------------------------------------------------------------------

#define HEADS 4

typedef _Float16 f16x8 __attribute__((ext_vector_type(8)));
typedef _Float16 f16x4 __attribute__((ext_vector_type(4)));
typedef float    f32x4 __attribute__((ext_vector_type(4)));

__device__ __forceinline__ float leaky02(float a) {
    return a >= 0.f ? a : 0.2f * a;
}

// ---------------------------------------------------------------------------
// W prep: fp32 [K=128][M] row-major -> fp16 fragment-ordered, grouped so
// each 64-col split's fragments are CONTIGUOUS (8192 halfs per group).
// ---------------------------------------------------------------------------
__device__ __forceinline__ void prep_one(const float* W, _Float16* Wf, int M, int o) {
    const int v = o & 7, lane = (o >> 3) & 63, rest = o >> 9;
    const int jl = rest & 3, t = (rest >> 2) & 3, grp = rest >> 4;
    const int k = t * 32 + (lane >> 4) * 8 + v;
    const int n = (grp * 4 + jl) * 16 + (lane & 15);
    Wf[o] = (_Float16)W[k * M + n];
}

__global__ __launch_bounds__(256) void prep_w4(
    const float* __restrict__ W1, _Float16* __restrict__ Wf1,
    const float* __restrict__ W2, _Float16* __restrict__ Wf2,
    const float* __restrict__ W3, _Float16* __restrict__ Wf3,
    const float* __restrict__ W4, _Float16* __restrict__ Wf4) {
    int o = blockIdx.x * 256 + threadIdx.x;
    if (o < 16384)       prep_one(W1, Wf1, 128, o);
    else if (o < 32768)  prep_one(W2, Wf2, 128, o - 16384);
    else if (o < 40960)  prep_one(W3, Wf3, 64, o - 32768);
    else if (o < 49152)  prep_one(W4, Wf4, 64, o - 40960);
}

// ---------------------------------------------------------------------------
// Layer-1 MFMA GEMM (dual) with fused alpha epilogue. 256 threads / 4 waves.
// Block = 64 rows x 64 cols (2 col-splits for M=128). One barrier.
// ---------------------------------------------------------------------------
template<int M, bool AHALF>
__global__ __launch_bounds__(256) void gemm_mfma_dual(
    const void* __restrict__ XA, const _Float16* __restrict__ WfA,
    const float* __restrict__ bA, _Float16* __restrict__ outA,
    const float* __restrict__ svA, const float* __restrict__ dvA,
    float* __restrict__ asA, float* __restrict__ adA,
    const void* __restrict__ XB, const _Float16* __restrict__ WfB,
    const float* __restrict__ bB, _Float16* __restrict__ outB,
    const float* __restrict__ svB, const float* __restrict__ dvB,
    float* __restrict__ asB, float* __restrict__ adB,
    int N, int nbs) {
    constexpr int NSPLIT = (M == 128) ? 2 : 1;  // col-splits
    constexpr int JT  = 4;                      // j-tiles per block (64 cols)
    constexpr int D   = M / HEADS;              // head dim (32 or 16)
    constexpr int HPB = 64 / D;                 // heads per block (2 or 4)
    constexpr int HL  = 4 / HPB;                // alpha lanes per head (2 or 1)
    constexpr int SA  = 136;                    // A stride (halfs): 272 B
    constexpr int WFH = JT * 4 * 64 * 8;        // 8192 halfs = 16 KiB
    __shared__ _Float16 lds_a[64 * SA];         // 17408 B
    __shared__ _Float16 lds_w[WFH];             // 16384 B

    const bool second = blockIdx.x >= (unsigned)nbs;
    const void* __restrict__ X      = second ? XB : XA;
    const _Float16* __restrict__ Wf = second ? WfB : WfA;
    const float* __restrict__ b     = second ? bB : bA;
    _Float16* __restrict__ out      = second ? outB : outA;
    const float* __restrict__ sv    = second ? svB : svA;
    const float* __restrict__ dv    = second ? dvB : dvA;
    float* __restrict__ asb         = second ? asB : asA;
    float* __restrict__ adb         = second ? adB : adA;
    const int b0    = second ? blockIdx.x - nbs : blockIdx.x;
    const int brow  = b0 / NSPLIT;
    const int split = b0 % NSPLIT;
    const int row0  = brow * 64;
    const int colb  = split * 64;               // global col base

    const int wave = threadIdx.x >> 6;
    const int lane = threadIdx.x & 63;
    const int m    = lane & 15;
    const int quad = lane >> 4;

    // ---- stage this split's Wf region -> LDS (flat coalesced f16x8)
    {
        const _Float16* wsrc = Wf + split * WFH;
        const int base = threadIdx.x * 8;       // 2048 halfs per iter
        #pragma unroll
        for (int it = 0; it < WFH / 2048; ++it) {
            f16x8 v = *(const f16x8*)(wsrc + it * 2048 + base);
            *(f16x8*)(lds_w + it * 2048 + base) = v;
        }
    }
    // ---- stage A -> LDS (coalesced rows, cvt fp32->fp16 if needed)
    if (AHALF) {
        #pragma unroll
        for (int it = 0; it < 4; ++it) {
            const int r = it * 16 + (threadIdx.x >> 4);
            const int k = (threadIdx.x & 15) * 8;
            int gr = row0 + r; if (gr >= N) gr = N - 1;
            f16x8 v = *(const f16x8*)((const _Float16*)X + (size_t)gr * 128 + k);
            *(f16x8*)(lds_a + r * SA + k) = v;
        }
    } else {
        #pragma unroll
        for (int it = 0; it < 8; ++it) {
            const int r = it * 8 + (threadIdx.x >> 5);
            const int k = (threadIdx.x & 31) * 4;
            int gr = row0 + r; if (gr >= N) gr = N - 1;
            float4 v = *(const float4*)((const float*)X + (size_t)gr * 128 + k);
            f16x4 h = {(_Float16)v.x, (_Float16)v.y, (_Float16)v.z, (_Float16)v.w};
            *(f16x4*)(lds_a + r * SA + k) = h;
        }
    }
    __syncthreads();   // the ONLY barrier

    f32x4 acc[JT];
    #pragma unroll
    for (int j = 0; j < JT; ++j) acc[j] = (f32x4){0.f, 0.f, 0.f, 0.f};

    const int ab = (wave * 16 + m) * SA;
    #pragma unroll
    for (int t = 0; t < 4; ++t) {
        f16x8 a = *(const f16x8*)(lds_a + ab + t * 32 + quad * 8);
        #pragma unroll
        for (int j = 0; j < JT; ++j) {
            f16x8 bf = *(const f16x8*)(lds_w + ((t * JT + j) * 64 + lane) * 8);
            acc[j] = __builtin_amdgcn_mfma_f32_16x16x32_f16(a, bf, acc[j], 0, 0, 0);
        }
    }

    // C/D: col = lane&15, row = quad*4 + reg -> OWN wave rows, stride SA.
    #pragma unroll
    for (int j = 0; j < JT; ++j) {
        const float bias = b[colb + j * 16 + m];
        #pragma unroll
        for (int r = 0; r < 4; ++r)
            lds_a[(wave * 16 + quad * 4 + r) * SA + j * 16 + m] =
                (_Float16)(acc[j][r] + bias);
    }

    // fused alpha: lane -> (row r, 16-col chunk q); HL lanes combine per head
    {
        const int r = lane >> 2;
        const int q = lane & 3;
        float ps = 0.f, pd = 0.f;
        #pragma unroll
        for (int j = 0; j < 4; ++j) {
            f16x4 v4 = *(const f16x4*)(&lds_a[(wave * 16 + r) * SA + q * 16 + 4 * j]);
            float4 s4 = *(const float4*)(sv + colb + q * 16 + 4 * j);
            float4 d4 = *(const float4*)(dv + colb + q * 16 + 4 * j);
            const float v0 = (float)v4[0], v1 = (float)v4[1],
                        v2 = (float)v4[2], v3 = (float)v4[3];
            ps += v0 * s4.x + v1 * s4.y + v2 * s4.z + v3 * s4.w;
            pd += v0 * d4.x + v1 * d4.y + v2 * d4.z + v3 * d4.w;
        }
        if (HL == 2) { ps += __shfl_xor(ps, 1); pd += __shfl_xor(pd, 1); }
        const int grow = row0 + wave * 16 + r;
        if (grow < N && (q & (HL - 1)) == 0) {
            const int hh = split * HPB + q / HL;
            asb[(size_t)grow * HEADS + hh] = ps;
            adb[(size_t)grow * HEADS + hh] = pd;
        }
    }

    // coalesced fp16 store of the wave's 16 rows x 64 local cols
    {
        const int lr = lane & 15;
        const int rq = lane >> 4;
        #pragma unroll
        for (int i = 0; i < 4; ++i) {
            const int lrow = i * 4 + rq;
            const int grow = row0 + wave * 16 + lrow;
            if (grow < N) {
                f16x4 v = *(const f16x4*)(&lds_a[(wave * 16 + lrow) * SA + lr * 4]);
                *(f16x4*)(out + (size_t)grow * M + colb + lr * 4) = v;
            }
        }
    }
}

// ---------------------------------------------------------------------------
// CSR build over the CONCATENATED 2N segment space.
// ---------------------------------------------------------------------------
__global__ __launch_bounds__(256) void hist_dual(
    const int* __restrict__ dst_pa, const int* __restrict__ dst_ap,
    int* __restrict__ counts, int N, int E) {
    const int eg = blockIdx.x * 256 + threadIdx.x;
    if (eg >= 2 * E) return;
    const int idx = (eg < E) ? dst_pa[eg] : (N + dst_ap[eg - E]);
    atomicAdd(counts + idx, 1);
}

// scan_blk + direction-major degree histogram (key = dir*64 + min(deg,63))
__global__ __launch_bounds__(256) void scan_blk(
    const int* __restrict__ in, int* __restrict__ out,
    int* __restrict__ bsum, int* __restrict__ bhist, int N2) {
    __shared__ int sh[256];
    __shared__ int lh[128];
    if (threadIdx.x < 128) lh[threadIdx.x] = 0;
    __syncthreads();
    const int N = N2 >> 1;
    const int base = blockIdx.x * 1024 + threadIdx.x * 4;
    int v[4]; int s = 0;
    #pragma unroll
    for (int j = 0; j < 4; ++j) {
        const int i = base + j;
        v[j] = (i < N2) ? in[i] : 0;
        s += v[j];
        if (i < N2) {
            int c = v[j] > 63 ? 63 : v[j];
            atomicAdd(&lh[(i >= N ? 64 : 0) + c], 1);
        }
    }
    sh[threadIdx.x] = s;
    __syncthreads();
    for (int off = 1; off < 256; off <<= 1) {
        int t = (threadIdx.x >= off) ? sh[threadIdx.x - off] : 0;
        __syncthreads();
        sh[threadIdx.x] += t;
        __syncthreads();
    }
    int run = sh[threadIdx.x] - s;
    #pragma unroll
    for (int j = 0; j < 4; ++j) {
        if (base + j < N2) out[base + j] = run;
        run += v[j];
    }
    if (threadIdx.x == 255) bsum[blockIdx.x] = sh[255];
    // all lh atomics completed before the scan's first barrier
    if (threadIdx.x < 128 && lh[threadIdx.x] > 0)
        atomicAdd(&bhist[threadIdx.x], lh[threadIdx.x]);
}

// dual exclusive scan in one dispatch: block 0 -> bsum[nb], block 1 -> bhist[128]
__global__ __launch_bounds__(256) void scan_sums2(
    int* __restrict__ bsum, int nb, int* __restrict__ bhist) {
    __shared__ int sh[256];
    int* buf   = (blockIdx.x == 0) ? bsum : bhist;
    const int n = (blockIdx.x == 0) ? nb : 128;
    int v = (threadIdx.x < n) ? buf[threadIdx.x] : 0;
    sh[threadIdx.x] = v;
    __syncthreads();
    for (int off = 1; off < 256; off <<= 1) {
        int t = (threadIdx.x >= off) ? sh[threadIdx.x - off] : 0;
        __syncthreads();
        sh[threadIdx.x] += t;
        __syncthreads();
    }
    if (threadIdx.x < n) buf[threadIdx.x] = sh[threadIdx.x] - v;
}

// fused: off2 finalize (+= block base) AND direction-major degree scatter
__global__ __launch_bounds__(256) void finalize_degscatter(
    int* __restrict__ off2, const int* __restrict__ bsum,
    const int* __restrict__ cnt, int* __restrict__ bcur,
    int* __restrict__ order, int n2) {
    __shared__ int lh[128];
    __shared__ int lbase[128];
    if (threadIdx.x < 128) lh[threadIdx.x] = 0;
    __syncthreads();
    const int N = n2 >> 1;
    const int base = blockIdx.x * 1024 + threadIdx.x * 4;
    const int add = bsum[blockIdx.x];
    int key[4], lpos[4];
    #pragma unroll
    for (int j = 0; j < 4; ++j) {
        const int i = base + j;
        if (i < n2) {
            off2[i] += add;
            int c = cnt[i]; if (c > 63) c = 63;
            key[j] = (i >= N ? 64 : 0) + c;
            lpos[j] = atomicAdd(&lh[key[j]], 1);
        }
    }
    __syncthreads();
    if (threadIdx.x < 128 && lh[threadIdx.x] > 0)
        lbase[threadIdx.x] = atomicAdd(&bcur[threadIdx.x], lh[threadIdx.x]);
    __syncthreads();
    #pragma unroll
    for (int j = 0; j < 4; ++j) {
        const int i = base + j;
        if (i < n2) order[lbase[key[j]] + lpos[j]] = i;
    }
}

__global__ __launch_bounds__(256) void scatter_dual(
    const int* __restrict__ src_pa, const int* __restrict__ dst_pa,
    const int* __restrict__ src_ap, const int* __restrict__ dst_ap,
    const int* __restrict__ offsets, int* __restrict__ cursor,
    int* __restrict__ perm, int N, int E) {
    const int eg = blockIdx.x * 256 + threadIdx.x;
    if (eg >= 2 * E) return;
    int idx, val;
    if (eg < E) { idx = dst_pa[eg];         val = src_pa[eg]; }
    else        { idx = N + dst_ap[eg - E]; val = src_ap[eg - E]; }
    const int pos = offsets[idx] + atomicAdd(cursor + idx, 1);
    perm[pos] = val;
}

// ---------------------------------------------------------------------------
// FUSED layer-1 aggregation + layer-2 projection + layer-2 alpha.
// 256 thr / 4 waves; per group of 16 same-direction nodes (degree-uniform,
// consumed descending = LPT). 2 barriers per group.
// ---------------------------------------------------------------------------
__global__ __launch_bounds__(256) void agg_proj_dual(
    const int* __restrict__ order,
    const int* __restrict__ perm, const int* __restrict__ offsets,
    const int* __restrict__ counts,
    const float* __restrict__ as1_0, const float* __restrict__ ad1_0,
    const _Float16* __restrict__ h1_0,
    const _Float16* __restrict__ Wf_0, const float* __restrict__ bb_0,
    _Float16* __restrict__ h2_0,
    const float* __restrict__ sv_0, const float* __restrict__ dv_0,
    float* __restrict__ as2_0, float* __restrict__ ad2_0,
    const float* __restrict__ as1_1, const float* __restrict__ ad1_1,
    const _Float16* __restrict__ h1_1,
    const _Float16* __restrict__ Wf_1, const float* __restrict__ bb_1,
    _Float16* __restrict__ h2_1,
    const float* __restrict__ sv_1, const float* __restrict__ dv_1,
    float* __restrict__ as2_1, float* __restrict__ ad2_1,
    int N, int GB) {
    constexpr int SAF = 136;                    // A-tile stride (halfs)
    constexpr int SH  = 72;                     // H-tile stride (halfs)
    __shared__ _Float16 ldsW[8192];             // 16 KiB W2 fragments
    __shared__ _Float16 ldsA[16 * SAF];         // 4352 B
    __shared__ _Float16 ldsH[16 * SH];          // 2304 B

    const bool d1 = blockIdx.x >= (unsigned)GB;
    const float*    __restrict__ as1 = d1 ? as1_1 : as1_0;
    const float*    __restrict__ ad1 = d1 ? ad1_1 : ad1_0;
    const _Float16* __restrict__ h1  = d1 ? h1_1 : h1_0;
    const _Float16* __restrict__ Wf  = d1 ? Wf_1 : Wf_0;
    const float*    __restrict__ bb  = d1 ? bb_1 : bb_0;
    _Float16*       __restrict__ h2  = d1 ? h2_1 : h2_0;
    const float*    __restrict__ sv  = d1 ? sv_1 : sv_0;
    const float*    __restrict__ dv  = d1 ? dv_1 : dv_0;
    float*          __restrict__ as2 = d1 ? as2_1 : as2_0;
    float*          __restrict__ ad2 = d1 ? ad2_1 : ad2_0;
    const int b0    = d1 ? blockIdx.x - GB : blockIdx.x;
    const int dbase = d1 ? N : 0;

    const int tid  = threadIdx.x;
    const int wave = tid >> 6;
    const int lane = tid & 63;
    const int nk   = tid >> 4;      // gather: node-lane 0..15
    const int fl   = tid & 15;      // gather: feature lane
    const int f0   = fl * 8;
    const int hh   = fl >> 2;       // gather: head (D=32)
    const int m    = lane & 15;     // mfma: row
    const int quad = lane >> 4;

    // ---- stage W2 fragments -> LDS once (visible after first barrier)
    {
        const int base = tid * 8;
        #pragma unroll
        for (int it = 0; it < 4; ++it) {
            f16x8 v = *(const f16x8*)(Wf + it * 2048 + base);
            *(f16x8*)(ldsW + it * 2048 + base) = v;
        }
    }

    const int nG = (N + 15) >> 4;
    for (int g = b0; g < nG; g += GB) {
        // ---------------- gather: this thread's 8 feats of node nk --------
        f16x8 rowv;
        #pragma unroll
        for (int j = 0; j < 8; ++j) rowv[j] = (_Float16)0.f;
        const int idx = g * 16 + nk;
        if (idx < N) {
            const int node_g = order[dbase + (N - 1 - idx)];
            const int node   = node_g - dbase;
            const int start  = offsets[node_g];
            const int cnt    = counts[node_g];
            const float ad   = ad1[(size_t)node * HEADS + hh];
            float den = 0.f;
            float acc[8];
            #pragma unroll
            for (int j = 0; j < 8; ++j) acc[j] = 0.f;
            const int last = cnt - 1;
            for (int i = 0; i < cnt; i += 4) {
                const int i1 = (i + 1 < cnt) ? i + 1 : last;
                const int i2 = (i + 2 < cnt) ? i + 2 : last;
                const int i3 = (i + 3 < cnt) ? i + 3 : last;
                const int s0 = perm[start + i];
                const int s1 = perm[start + i1];
                const int s2 = perm[start + i2];
                const int s3 = perm[start + i3];
                const float a0 = as1[(size_t)s0 * HEADS + hh];
                const float a1 = as1[(size_t)s1 * HEADS + hh];
                const float a2 = as1[(size_t)s2 * HEADS + hh];
                const float a3 = as1[(size_t)s3 * HEADS + hh];
                f16x8 h0 = *(const f16x8*)(h1 + (size_t)s0 * 128 + f0);
                f16x8 hb = *(const f16x8*)(h1 + (size_t)s1 * 128 + f0);
                f16x8 hc = *(const f16x8*)(h1 + (size_t)s2 * 128 + f0);
                f16x8 hd = *(const f16x8*)(h1 + (size_t)s3 * 128 + f0);
                const float e0 = __expf(leaky02(a0 + ad));
                float e1 = __expf(leaky02(a1 + ad));
                float e2 = __expf(leaky02(a2 + ad));
                float e3 = __expf(leaky02(a3 + ad));
                if (i + 1 >= cnt) e1 = 0.f;
                if (i + 2 >= cnt) e2 = 0.f;
                if (i + 3 >= cnt) e3 = 0.f;
                den += (e0 + e1) + (e2 + e3);
                #pragma unroll
                for (int j = 0; j < 8; ++j)
                    acc[j] += e0 * (float)h0[j] + e1 * (float)hb[j]
                            + e2 * (float)hc[j] + e3 * (float)hd[j];
            }
            const float inv = 1.f / (den + 1e-16f);
            #pragma unroll
            for (int j = 0; j < 8; ++j)
                rowv[j] = (_Float16)fmaxf(acc[j] * inv, 0.f);
        }
        *(f16x8*)(ldsA + nk * SAF + f0) = rowv;
        __syncthreads();

        // ---------------- projection: wave computes cols 16w..16w+15 ------
        f32x4 c = (f32x4){0.f, 0.f, 0.f, 0.f};
        const int ab = m * SAF;
        #pragma unroll
        for (int t = 0; t < 4; ++t) {
            f16x8 a  = *(const f16x8*)(ldsA + ab + t * 32 + quad * 8);
            f16x8 bf = *(const f16x8*)(ldsW + ((t * 4 + wave) * 64 + lane) * 8);
            c = __builtin_amdgcn_mfma_f32_16x16x32_f16(a, bf, c, 0, 0, 0);
        }
        const float bias = bb[wave * 16 + m];
        #pragma unroll
        for (int r = 0; r < 4; ++r)
            ldsH[(quad * 4 + r) * SH + wave * 16 + m] = (_Float16)(c[r] + bias);
        __syncthreads();

        // ---------------- layer-2 alpha (wave 0: 16 rows x 4 heads) -------
        if (wave == 0) {
            const int r = lane >> 2;
            const int q = lane & 3;
            const int aidx = g * 16 + r;
            if (aidx < N) {
                const int anode = order[dbase + (N - 1 - aidx)] - dbase;
                float ps = 0.f, pd = 0.f;
                #pragma unroll
                for (int jj = 0; jj < 4; ++jj) {
                    f16x4 v4 = *(const f16x4*)(&ldsH[r * SH + q * 16 + 4 * jj]);
                    float4 s4 = *(const float4*)(sv + q * 16 + 4 * jj);
                    float4 d4 = *(const float4*)(dv + q * 16 + 4 * jj);
                    const float v0 = (float)v4[0], v1 = (float)v4[1],
                                v2 = (float)v4[2], v3 = (float)v4[3];
                    ps += v0 * s4.x + v1 * s4.y + v2 * s4.z + v3 * s4.w;
                    pd += v0 * d4.x + v1 * d4.y + v2 * d4.z + v3 * d4.w;
                }
                as2[(size_t)anode * HEADS + q] = ps;
                ad2[(size_t)anode * HEADS + q] = pd;
            }
        }
        // ---------------- h2 store: wave w -> rows 4w..4w+3 ---------------
        {
            const int lr  = lane & 15;
            const int rq  = lane >> 4;
            const int row = wave * 4 + rq;
            const int sidx = g * 16 + row;
            if (sidx < N) {
                const int snode = order[dbase + (N - 1 - sidx)] - dbase;
                f16x4 v = *(const f16x4*)(&ldsH[row * SH + lr * 4]);
                *(f16x4*)(h2 + (size_t)snode * 64 + lr * 4) = v;
            }
        }
        // no barrier here: next gather only touches ldsA (guarded by the
        // post-MFMA barrier); ldsH readers complete in program order.
    }
}

// ---------------------------------------------------------------------------
// Layer-2 fused per-dst softmax + aggregation.
// ---------------------------------------------------------------------------
template<int F, int D>
__global__ __launch_bounds__(256) void csr_attn_agg_dual(
    const int* __restrict__ order,
    const int* __restrict__ perm, const int* __restrict__ offsets,
    const int* __restrict__ counts,
    const float* __restrict__ asrcP, const float* __restrict__ adstP,
    const _Float16* __restrict__ hP, _Float16* __restrict__ outA,
    const float* __restrict__ asrcA, const float* __restrict__ adstA,
    const _Float16* __restrict__ hA, _Float16* __restrict__ outP,
    int N) {
    constexpr int LPN = F / 8;
    const int gid  = blockIdx.x * 256 + threadIdx.x;
    const int slotF = gid / LPN;
    const int lane  = gid % LPN;
    if (slotF >= 2 * N) return;
    const int slot = 2 * N - 1 - slotF;          // descending degree (LPT)
    const int node_g = order[slot];
    const bool second = node_g >= N;
    const int node = second ? node_g - N : node_g;
    const float* __restrict__ asrc    = second ? asrcA : asrcP;
    const float* __restrict__ adst    = second ? adstA : adstP;
    const _Float16* __restrict__ hsrc = second ? hA : hP;
    _Float16* __restrict__ out        = second ? outP : outA;

    const int start = offsets[node_g];
    const int cnt   = counts[node_g];
    const int f0 = lane * 8;
    const int h  = f0 / D;
    const float ad = adst[(size_t)node * HEADS + h];

    float den = 0.f;
    float acc[8];
    #pragma unroll
    for (int j = 0; j < 8; ++j) acc[j] = 0.f;
    const int last = cnt - 1;
    for (int i = 0; i < cnt; i += 4) {
        const int i1 = (i + 1 < cnt) ? i + 1 : last;
        const int i2 = (i + 2 < cnt) ? i + 2 : last;
        const int i3 = (i + 3 < cnt) ? i + 3 : last;
        const int s0 = perm[start + i];
        const int s1 = perm[start + i1];
        const int s2 = perm[start + i2];
        const int s3 = perm[start + i3];
        const float a0 = asrc[(size_t)s0 * HEADS + h];
        const float a1 = asrc[(size_t)s1 * HEADS + h];
        const float a2 = asrc[(size_t)s2 * HEADS + h];
        const float a3 = asrc[(size_t)s3 * HEADS + h];
        f16x8 h0 = *(const f16x8*)(hsrc + (size_t)s0 * F + f0);
        f16x8 h1 = *(const f16x8*)(hsrc + (size_t)s1 * F + f0);
        f16x8 h2 = *(const f16x8*)(hsrc + (size_t)s2 * F + f0);
        f16x8 h3 = *(const f16x8*)(hsrc + (size_t)s3 * F + f0);
        const float e0 = __expf(leaky02(a0 + ad));
        float e1 = __expf(leaky02(a1 + ad));
        float e2 = __expf(leaky02(a2 + ad));
        float e3 = __expf(leaky02(a3 + ad));
        if (i + 1 >= cnt) e1 = 0.f;
        if (i + 2 >= cnt) e2 = 0.f;
        if (i + 3 >= cnt) e3 = 0.f;
        den += (e0 + e1) + (e2 + e3);
        #pragma unroll
        for (int j = 0; j < 8; ++j)
            acc[j] += e0 * (float)h0[j] + e1 * (float)h1[j]
                    + e2 * (float)h2[j] + e3 * (float)h3[j];
    }
    const float inv = 1.f / (den + 1e-16f);
    f16x8 o;
    #pragma unroll
    for (int j = 0; j < 8; ++j)
        o[j] = (_Float16)fmaxf(acc[j] * inv, 0.f);
    *(f16x8*)(out + (size_t)node * F + f0) = o;
}

// ---------------------------------------------------------------------------
// Final: out[l] = dot(zp[eli0[l]], za[eli1[l]]), 64 fp16 feats -> fp32.
// ---------------------------------------------------------------------------
__global__ __launch_bounds__(256) void edge_dot(
    const int* __restrict__ eli, const _Float16* __restrict__ zp,
    const _Float16* __restrict__ za, float* __restrict__ out, int L) {
    constexpr int LPE = 8;
    const int gid  = blockIdx.x * blockDim.x + threadIdx.x;
    const int e    = gid / LPE;
    const int lane = gid % LPE;
    if (e >= L) return;
    const int p = eli[e], a = eli[(size_t)L + e];
    f16x8 pv = *(const f16x8*)(zp + (size_t)p * 64 + lane * 8);
    f16x8 av = *(const f16x8*)(za + (size_t)a * 64 + lane * 8);
    float s = 0.f;
    #pragma unroll
    for (int j = 0; j < 8; ++j) s += (float)pv[j] * (float)av[j];
    #pragma unroll
    for (int off = 4; off > 0; off >>= 1) s += __shfl_xor(s, off);
    if (lane == 0) out[e] = s;
}

// ---------------------------------------------------------------------------
static inline int cdiv(long long a, long long b) { return (int)((a + b - 1) / b); }

extern "C" void kernel_launch(void* const* d_in, const int* in_sizes, int n_in,
                              void* d_out, int out_size, void* d_ws, size_t ws_size,
                              hipStream_t stream) {
    const float* x_p  = (const float*)d_in[0];
    const float* x_a  = (const float*)d_in[1];
    const int* ei_pa  = (const int*)d_in[2];
    const int* ei_ap  = (const int*)d_in[3];
    const int* eli    = (const int*)d_in[4];
    const float* p1W = (const float*)d_in[5];
    const float* p1b = (const float*)d_in[6];
    const float* a1W = (const float*)d_in[7];
    const float* a1b = (const float*)d_in[8];
    const float* s1pa = (const float*)d_in[9];
    const float* d1pa = (const float*)d_in[10];
    const float* s1ap = (const float*)d_in[11];
    const float* d1ap = (const float*)d_in[12];
    // 13..15: k1W, k1b, q1 — dead (single-metapath group == identity)
    const float* p2W = (const float*)d_in[16];
    const float* p2b = (const float*)d_in[17];
    const float* a2W = (const float*)d_in[18];
    const float* a2b = (const float*)d_in[19];
    const float* s2pa = (const float*)d_in[20];
    const float* d2pa = (const float*)d_in[21];
    const float* s2ap = (const float*)d_in[22];
    const float* d2ap = (const float*)d_in[23];
    // 24..26: k2W, k2b, q2 — dead

    const int NP = in_sizes[0] / 128;
    const int E  = in_sizes[2] / 2;
    const int L  = in_sizes[4] / 2;
    const int N  = NP;  // NP == NA

    // ---- workspace layout ----
    char* ws = (char*)d_ws;
    size_t off = 0;
    auto alloc = [&](size_t bytes) -> char* {
        char* p = ws + off;
        off += (bytes + 255) & ~(size_t)255;
        return p;
    };
    _Float16* h_p1   = (_Float16*)alloc((size_t)N * 128 * 2);
    _Float16* h_a1   = (_Float16*)alloc((size_t)N * 128 * 2);
    _Float16* h_p2   = (_Float16*)alloc((size_t)N * 64 * 2);
    _Float16* h_a2   = (_Float16*)alloc((size_t)N * 64 * 2);
    _Float16* out_p2 = (_Float16*)alloc((size_t)N * 64 * 2);
    _Float16* out_a2 = (_Float16*)alloc((size_t)N * 64 * 2);
    float* asrc_pa = (float*)alloc((size_t)N * HEADS * 4);
    float* adst_pa = (float*)alloc((size_t)N * HEADS * 4);
    float* asrc_ap = (float*)alloc((size_t)N * HEADS * 4);
    float* adst_ap = (float*)alloc((size_t)N * HEADS * 4);
    float* as2_pa  = (float*)alloc((size_t)N * HEADS * 4);
    float* ad2_pa  = (float*)alloc((size_t)N * HEADS * 4);
    float* as2_ap  = (float*)alloc((size_t)N * HEADS * 4);
    float* ad2_ap  = (float*)alloc((size_t)N * HEADS * 4);
    _Float16* Wf1p = (_Float16*)alloc(16384 * 2);
    _Float16* Wf1a = (_Float16*)alloc(16384 * 2);
    _Float16* Wf2p = (_Float16*)alloc(8192 * 2);
    _Float16* Wf2a = (_Float16*)alloc(8192 * 2);
    // cnt2 / cursor2 / bhist are contiguous: one memset covers them
    int* cnt2    = (int*)alloc((size_t)2 * N * 4);
    int* cursor2 = (int*)alloc((size_t)2 * N * 4);
    int* bhist   = (int*)alloc(512);            // 128 ints
    int* off2    = (int*)alloc((size_t)2 * N * 4);
    int* perm2   = (int*)alloc((size_t)2 * E * 4);
    int* order2  = (int*)alloc((size_t)2 * N * 4);
    int* bsum    = (int*)alloc(256 * 4);

    const int* src_pa = ei_pa;       // papers
    const int* dst_pa = ei_pa + E;   // authors
    const int* src_ap = ei_ap;       // authors
    const int* dst_ap = ei_ap + E;   // papers

    const int N2 = 2 * N;
    const int nbScan = cdiv(N2, 1024);

    // ================= prep + CSR build + direction-major degree sort =====
    prep_w4<<<cdiv(49152, 256), 256, 0, stream>>>(p1W, Wf1p, a1W, Wf1a, p2W, Wf2p, a2W, Wf2a);
    hipMemsetAsync(cnt2, 0, ((size_t)4 * N + 128) * 4, stream);  // cnt2+cursor2+bhist
    hist_dual<<<cdiv((long long)2 * E, 256), 256, 0, stream>>>(dst_pa, dst_ap, cnt2, N, E);
    scan_blk<<<nbScan, 256, 0, stream>>>(cnt2, off2, bsum, bhist, N2);
    scan_sums2<<<2, 256, 0, stream>>>(bsum, nbScan, bhist);
    finalize_degscatter<<<nbScan, 256, 0, stream>>>(off2, bsum, cnt2, bhist, order2, N2);
    scatter_dual<<<cdiv((long long)2 * E, 256), 256, 0, stream>>>(
        src_pa, dst_pa, src_ap, dst_ap, off2, cursor2, perm2, N, E);

    const int nbs1 = cdiv(N, 64) * 2;   // 64-row tiles x 2 col-splits (M=128)

    // ================= Layer 1 GEMM =================
    gemm_mfma_dual<128, false><<<2 * nbs1, 256, 0, stream>>>(
        x_p, Wf1p, p1b, h_p1, s1pa, d1ap, asrc_pa, adst_ap,
        x_a, Wf1a, a1b, h_a1, s1ap, d1pa, asrc_ap, adst_pa, N, nbs1);

    // ================= Fused agg1 + layer-2 projection =================
    // dir0 (author dst): gather h_p1 w/ (asrc_pa, adst_pa); proj a2W -> h_a2
    // dir1 (paper dst):  gather h_a1 w/ (asrc_ap, adst_ap); proj p2W -> h_p2
    const int GB = 768;                 // 1536 blocks -> ~6 resident/CU
    agg_proj_dual<<<2 * GB, 256, 0, stream>>>(
        order2, perm2, off2, cnt2,
        asrc_pa, adst_pa, h_p1, Wf2a, a2b, h_a2, s2ap, d2pa, as2_ap, ad2_pa,
        asrc_ap, adst_ap, h_a1, Wf2p, p2b, h_p2, s2pa, d2ap, as2_pa, ad2_ap,
        N, GB);

    // ================= Layer 2 aggregation =================
    csr_attn_agg_dual<64, 16><<<cdiv((long long)N2 * 8, 256), 256, 0, stream>>>(
        order2, perm2, off2, cnt2,
        as2_pa, ad2_pa, h_p2, out_a2,
        as2_ap, ad2_ap, h_a2, out_p2, N);

    // ================= Final dot =================
    edge_dot<<<cdiv((long long)L * 8, 256), 256, 0, stream>>>(
        eli, out_p2, out_a2, (float*)d_out, L);
}

// Round 9
// 405.837 us; speedup vs baseline: 1.0343x; 1.0343x over previous
//
#include <hip/hip_runtime.h>

// ---------------------------------------------------------------------------
// HAN link-prediction forward. fp16 MFMA GEMMs + fp16 intermediates,
// fp32 alpha tables / accumulation / output.
//   - _group with one metapath == identity (k*W/k*b/q* are dead params)
//   - concatenated 2N-segment CSR (one build serves both directions+layers)
//   - DIRECTION-MAJOR degree sort (128 buckets), consumed descending (LPT)
//   - FUSED agg1 + layer-2 projection (agg_proj_dual); grid 2x625 (=r7 best:
//     r8's 2x768 LOWERED occupancy 47->38% and FETCH +11MB — wider grids
//     trade L2 gather locality for TLP at a net loss here)
//   - CSR chain consolidated 9 -> 6 dispatches (kept from r8: worth ~12us)
//   - agg: masked unroll-4, 16B f16x8 gathers (byte-bound at ~3.9 TB/s)
//   - GEMM1: one-shot 64-row x 64-col blocks, 33.8 KiB LDS, ONE barrier
// ---------------------------------------------------------------------------

#define HEADS 4

typedef _Float16 f16x8 __attribute__((ext_vector_type(8)));
typedef _Float16 f16x4 __attribute__((ext_vector_type(4)));
typedef float    f32x4 __attribute__((ext_vector_type(4)));

__device__ __forceinline__ float leaky02(float a) {
    return a >= 0.f ? a : 0.2f * a;
}

// ---------------------------------------------------------------------------
// W prep: fp32 [K=128][M] row-major -> fp16 fragment-ordered, grouped so
// each 64-col split's fragments are CONTIGUOUS (8192 halfs per group).
// ---------------------------------------------------------------------------
__device__ __forceinline__ void prep_one(const float* W, _Float16* Wf, int M, int o) {
    const int v = o & 7, lane = (o >> 3) & 63, rest = o >> 9;
    const int jl = rest & 3, t = (rest >> 2) & 3, grp = rest >> 4;
    const int k = t * 32 + (lane >> 4) * 8 + v;
    const int n = (grp * 4 + jl) * 16 + (lane & 15);
    Wf[o] = (_Float16)W[k * M + n];
}

__global__ __launch_bounds__(256) void prep_w4(
    const float* __restrict__ W1, _Float16* __restrict__ Wf1,
    const float* __restrict__ W2, _Float16* __restrict__ Wf2,
    const float* __restrict__ W3, _Float16* __restrict__ Wf3,
    const float* __restrict__ W4, _Float16* __restrict__ Wf4) {
    int o = blockIdx.x * 256 + threadIdx.x;
    if (o < 16384)       prep_one(W1, Wf1, 128, o);
    else if (o < 32768)  prep_one(W2, Wf2, 128, o - 16384);
    else if (o < 40960)  prep_one(W3, Wf3, 64, o - 32768);
    else if (o < 49152)  prep_one(W4, Wf4, 64, o - 40960);
}

// ---------------------------------------------------------------------------
// Layer-1 MFMA GEMM (dual) with fused alpha epilogue. 256 threads / 4 waves.
// Block = 64 rows x 64 cols (2 col-splits for M=128). One barrier.
// ---------------------------------------------------------------------------
template<int M, bool AHALF>
__global__ __launch_bounds__(256) void gemm_mfma_dual(
    const void* __restrict__ XA, const _Float16* __restrict__ WfA,
    const float* __restrict__ bA, _Float16* __restrict__ outA,
    const float* __restrict__ svA, const float* __restrict__ dvA,
    float* __restrict__ asA, float* __restrict__ adA,
    const void* __restrict__ XB, const _Float16* __restrict__ WfB,
    const float* __restrict__ bB, _Float16* __restrict__ outB,
    const float* __restrict__ svB, const float* __restrict__ dvB,
    float* __restrict__ asB, float* __restrict__ adB,
    int N, int nbs) {
    constexpr int NSPLIT = (M == 128) ? 2 : 1;  // col-splits
    constexpr int JT  = 4;                      // j-tiles per block (64 cols)
    constexpr int D   = M / HEADS;              // head dim (32 or 16)
    constexpr int HPB = 64 / D;                 // heads per block (2 or 4)
    constexpr int HL  = 4 / HPB;                // alpha lanes per head (2 or 1)
    constexpr int SA  = 136;                    // A stride (halfs): 272 B
    constexpr int WFH = JT * 4 * 64 * 8;        // 8192 halfs = 16 KiB
    __shared__ _Float16 lds_a[64 * SA];         // 17408 B
    __shared__ _Float16 lds_w[WFH];             // 16384 B

    const bool second = blockIdx.x >= (unsigned)nbs;
    const void* __restrict__ X      = second ? XB : XA;
    const _Float16* __restrict__ Wf = second ? WfB : WfA;
    const float* __restrict__ b     = second ? bB : bA;
    _Float16* __restrict__ out      = second ? outB : outA;
    const float* __restrict__ sv    = second ? svB : svA;
    const float* __restrict__ dv    = second ? dvB : dvA;
    float* __restrict__ asb         = second ? asB : asA;
    float* __restrict__ adb         = second ? adB : adA;
    const int b0    = second ? blockIdx.x - nbs : blockIdx.x;
    const int brow  = b0 / NSPLIT;
    const int split = b0 % NSPLIT;
    const int row0  = brow * 64;
    const int colb  = split * 64;               // global col base

    const int wave = threadIdx.x >> 6;
    const int lane = threadIdx.x & 63;
    const int m    = lane & 15;
    const int quad = lane >> 4;

    // ---- stage this split's Wf region -> LDS (flat coalesced f16x8)
    {
        const _Float16* wsrc = Wf + split * WFH;
        const int base = threadIdx.x * 8;       // 2048 halfs per iter
        #pragma unroll
        for (int it = 0; it < WFH / 2048; ++it) {
            f16x8 v = *(const f16x8*)(wsrc + it * 2048 + base);
            *(f16x8*)(lds_w + it * 2048 + base) = v;
        }
    }
    // ---- stage A -> LDS (coalesced rows, cvt fp32->fp16 if needed)
    if (AHALF) {
        #pragma unroll
        for (int it = 0; it < 4; ++it) {
            const int r = it * 16 + (threadIdx.x >> 4);
            const int k = (threadIdx.x & 15) * 8;
            int gr = row0 + r; if (gr >= N) gr = N - 1;
            f16x8 v = *(const f16x8*)((const _Float16*)X + (size_t)gr * 128 + k);
            *(f16x8*)(lds_a + r * SA + k) = v;
        }
    } else {
        #pragma unroll
        for (int it = 0; it < 8; ++it) {
            const int r = it * 8 + (threadIdx.x >> 5);
            const int k = (threadIdx.x & 31) * 4;
            int gr = row0 + r; if (gr >= N) gr = N - 1;
            float4 v = *(const float4*)((const float*)X + (size_t)gr * 128 + k);
            f16x4 h = {(_Float16)v.x, (_Float16)v.y, (_Float16)v.z, (_Float16)v.w};
            *(f16x4*)(lds_a + r * SA + k) = h;
        }
    }
    __syncthreads();   // the ONLY barrier

    f32x4 acc[JT];
    #pragma unroll
    for (int j = 0; j < JT; ++j) acc[j] = (f32x4){0.f, 0.f, 0.f, 0.f};

    const int ab = (wave * 16 + m) * SA;
    #pragma unroll
    for (int t = 0; t < 4; ++t) {
        f16x8 a = *(const f16x8*)(lds_a + ab + t * 32 + quad * 8);
        #pragma unroll
        for (int j = 0; j < JT; ++j) {
            f16x8 bf = *(const f16x8*)(lds_w + ((t * JT + j) * 64 + lane) * 8);
            acc[j] = __builtin_amdgcn_mfma_f32_16x16x32_f16(a, bf, acc[j], 0, 0, 0);
        }
    }

    // C/D: col = lane&15, row = quad*4 + reg -> OWN wave rows, stride SA.
    #pragma unroll
    for (int j = 0; j < JT; ++j) {
        const float bias = b[colb + j * 16 + m];
        #pragma unroll
        for (int r = 0; r < 4; ++r)
            lds_a[(wave * 16 + quad * 4 + r) * SA + j * 16 + m] =
                (_Float16)(acc[j][r] + bias);
    }

    // fused alpha: lane -> (row r, 16-col chunk q); HL lanes combine per head
    {
        const int r = lane >> 2;
        const int q = lane & 3;
        float ps = 0.f, pd = 0.f;
        #pragma unroll
        for (int j = 0; j < 4; ++j) {
            f16x4 v4 = *(const f16x4*)(&lds_a[(wave * 16 + r) * SA + q * 16 + 4 * j]);
            float4 s4 = *(const float4*)(sv + colb + q * 16 + 4 * j);
            float4 d4 = *(const float4*)(dv + colb + q * 16 + 4 * j);
            const float v0 = (float)v4[0], v1 = (float)v4[1],
                        v2 = (float)v4[2], v3 = (float)v4[3];
            ps += v0 * s4.x + v1 * s4.y + v2 * s4.z + v3 * s4.w;
            pd += v0 * d4.x + v1 * d4.y + v2 * d4.z + v3 * d4.w;
        }
        if (HL == 2) { ps += __shfl_xor(ps, 1); pd += __shfl_xor(pd, 1); }
        const int grow = row0 + wave * 16 + r;
        if (grow < N && (q & (HL - 1)) == 0) {
            const int hh = split * HPB + q / HL;
            asb[(size_t)grow * HEADS + hh] = ps;
            adb[(size_t)grow * HEADS + hh] = pd;
        }
    }

    // coalesced fp16 store of the wave's 16 rows x 64 local cols
    {
        const int lr = lane & 15;
        const int rq = lane >> 4;
        #pragma unroll
        for (int i = 0; i < 4; ++i) {
            const int lrow = i * 4 + rq;
            const int grow = row0 + wave * 16 + lrow;
            if (grow < N) {
                f16x4 v = *(const f16x4*)(&lds_a[(wave * 16 + lrow) * SA + lr * 4]);
                *(f16x4*)(out + (size_t)grow * M + colb + lr * 4) = v;
            }
        }
    }
}

// ---------------------------------------------------------------------------
// CSR build over the CONCATENATED 2N segment space.
// ---------------------------------------------------------------------------
__global__ __launch_bounds__(256) void hist_dual(
    const int* __restrict__ dst_pa, const int* __restrict__ dst_ap,
    int* __restrict__ counts, int N, int E) {
    const int eg = blockIdx.x * 256 + threadIdx.x;
    if (eg >= 2 * E) return;
    const int idx = (eg < E) ? dst_pa[eg] : (N + dst_ap[eg - E]);
    atomicAdd(counts + idx, 1);
}

// scan_blk + direction-major degree histogram (key = dir*64 + min(deg,63))
__global__ __launch_bounds__(256) void scan_blk(
    const int* __restrict__ in, int* __restrict__ out,
    int* __restrict__ bsum, int* __restrict__ bhist, int N2) {
    __shared__ int sh[256];
    __shared__ int lh[128];
    if (threadIdx.x < 128) lh[threadIdx.x] = 0;
    __syncthreads();
    const int N = N2 >> 1;
    const int base = blockIdx.x * 1024 + threadIdx.x * 4;
    int v[4]; int s = 0;
    #pragma unroll
    for (int j = 0; j < 4; ++j) {
        const int i = base + j;
        v[j] = (i < N2) ? in[i] : 0;
        s += v[j];
        if (i < N2) {
            int c = v[j] > 63 ? 63 : v[j];
            atomicAdd(&lh[(i >= N ? 64 : 0) + c], 1);
        }
    }
    sh[threadIdx.x] = s;
    __syncthreads();
    for (int off = 1; off < 256; off <<= 1) {
        int t = (threadIdx.x >= off) ? sh[threadIdx.x - off] : 0;
        __syncthreads();
        sh[threadIdx.x] += t;
        __syncthreads();
    }
    int run = sh[threadIdx.x] - s;
    #pragma unroll
    for (int j = 0; j < 4; ++j) {
        if (base + j < N2) out[base + j] = run;
        run += v[j];
    }
    if (threadIdx.x == 255) bsum[blockIdx.x] = sh[255];
    // all lh atomics completed before the scan's first barrier
    if (threadIdx.x < 128 && lh[threadIdx.x] > 0)
        atomicAdd(&bhist[threadIdx.x], lh[threadIdx.x]);
}

// dual exclusive scan in one dispatch: block 0 -> bsum[nb], block 1 -> bhist[128]
__global__ __launch_bounds__(256) void scan_sums2(
    int* __restrict__ bsum, int nb, int* __restrict__ bhist) {
    __shared__ int sh[256];
    int* buf   = (blockIdx.x == 0) ? bsum : bhist;
    const int n = (blockIdx.x == 0) ? nb : 128;
    int v = (threadIdx.x < n) ? buf[threadIdx.x] : 0;
    sh[threadIdx.x] = v;
    __syncthreads();
    for (int off = 1; off < 256; off <<= 1) {
        int t = (threadIdx.x >= off) ? sh[threadIdx.x - off] : 0;
        __syncthreads();
        sh[threadIdx.x] += t;
        __syncthreads();
    }
    if (threadIdx.x < n) buf[threadIdx.x] = sh[threadIdx.x] - v;
}

// fused: off2 finalize (+= block base) AND direction-major degree scatter
__global__ __launch_bounds__(256) void finalize_degscatter(
    int* __restrict__ off2, const int* __restrict__ bsum,
    const int* __restrict__ cnt, int* __restrict__ bcur,
    int* __restrict__ order, int n2) {
    __shared__ int lh[128];
    __shared__ int lbase[128];
    if (threadIdx.x < 128) lh[threadIdx.x] = 0;
    __syncthreads();
    const int N = n2 >> 1;
    const int base = blockIdx.x * 1024 + threadIdx.x * 4;
    const int add = bsum[blockIdx.x];
    int key[4], lpos[4];
    #pragma unroll
    for (int j = 0; j < 4; ++j) {
        const int i = base + j;
        if (i < n2) {
            off2[i] += add;
            int c = cnt[i]; if (c > 63) c = 63;
            key[j] = (i >= N ? 64 : 0) + c;
            lpos[j] = atomicAdd(&lh[key[j]], 1);
        }
    }
    __syncthreads();
    if (threadIdx.x < 128 && lh[threadIdx.x] > 0)
        lbase[threadIdx.x] = atomicAdd(&bcur[threadIdx.x], lh[threadIdx.x]);
    __syncthreads();
    #pragma unroll
    for (int j = 0; j < 4; ++j) {
        const int i = base + j;
        if (i < n2) order[lbase[key[j]] + lpos[j]] = i;
    }
}

__global__ __launch_bounds__(256) void scatter_dual(
    const int* __restrict__ src_pa, const int* __restrict__ dst_pa,
    const int* __restrict__ src_ap, const int* __restrict__ dst_ap,
    const int* __restrict__ offsets, int* __restrict__ cursor,
    int* __restrict__ perm, int N, int E) {
    const int eg = blockIdx.x * 256 + threadIdx.x;
    if (eg >= 2 * E) return;
    int idx, val;
    if (eg < E) { idx = dst_pa[eg];         val = src_pa[eg]; }
    else        { idx = N + dst_ap[eg - E]; val = src_ap[eg - E]; }
    const int pos = offsets[idx] + atomicAdd(cursor + idx, 1);
    perm[pos] = val;
}

// ---------------------------------------------------------------------------
// FUSED layer-1 aggregation + layer-2 projection + layer-2 alpha.
// 256 thr / 4 waves; per group of 16 same-direction nodes (degree-uniform,
// consumed descending = LPT). 2 barriers per group.
// ---------------------------------------------------------------------------
__global__ __launch_bounds__(256) void agg_proj_dual(
    const int* __restrict__ order,
    const int* __restrict__ perm, const int* __restrict__ offsets,
    const int* __restrict__ counts,
    const float* __restrict__ as1_0, const float* __restrict__ ad1_0,
    const _Float16* __restrict__ h1_0,
    const _Float16* __restrict__ Wf_0, const float* __restrict__ bb_0,
    _Float16* __restrict__ h2_0,
    const float* __restrict__ sv_0, const float* __restrict__ dv_0,
    float* __restrict__ as2_0, float* __restrict__ ad2_0,
    const float* __restrict__ as1_1, const float* __restrict__ ad1_1,
    const _Float16* __restrict__ h1_1,
    const _Float16* __restrict__ Wf_1, const float* __restrict__ bb_1,
    _Float16* __restrict__ h2_1,
    const float* __restrict__ sv_1, const float* __restrict__ dv_1,
    float* __restrict__ as2_1, float* __restrict__ ad2_1,
    int N, int GB) {
    constexpr int SAF = 136;                    // A-tile stride (halfs)
    constexpr int SH  = 72;                     // H-tile stride (halfs)
    __shared__ _Float16 ldsW[8192];             // 16 KiB W2 fragments
    __shared__ _Float16 ldsA[16 * SAF];         // 4352 B
    __shared__ _Float16 ldsH[16 * SH];          // 2304 B

    const bool d1 = blockIdx.x >= (unsigned)GB;
    const float*    __restrict__ as1 = d1 ? as1_1 : as1_0;
    const float*    __restrict__ ad1 = d1 ? ad1_1 : ad1_0;
    const _Float16* __restrict__ h1  = d1 ? h1_1 : h1_0;
    const _Float16* __restrict__ Wf  = d1 ? Wf_1 : Wf_0;
    const float*    __restrict__ bb  = d1 ? bb_1 : bb_0;
    _Float16*       __restrict__ h2  = d1 ? h2_1 : h2_0;
    const float*    __restrict__ sv  = d1 ? sv_1 : sv_0;
    const float*    __restrict__ dv  = d1 ? dv_1 : dv_0;
    float*          __restrict__ as2 = d1 ? as2_1 : as2_0;
    float*          __restrict__ ad2 = d1 ? ad2_1 : ad2_0;
    const int b0    = d1 ? blockIdx.x - GB : blockIdx.x;
    const int dbase = d1 ? N : 0;

    const int tid  = threadIdx.x;
    const int wave = tid >> 6;
    const int lane = tid & 63;
    const int nk   = tid >> 4;      // gather: node-lane 0..15
    const int fl   = tid & 15;      // gather: feature lane
    const int f0   = fl * 8;
    const int hh   = fl >> 2;       // gather: head (D=32)
    const int m    = lane & 15;     // mfma: row
    const int quad = lane >> 4;

    // ---- stage W2 fragments -> LDS once (visible after first barrier)
    {
        const int base = tid * 8;
        #pragma unroll
        for (int it = 0; it < 4; ++it) {
            f16x8 v = *(const f16x8*)(Wf + it * 2048 + base);
            *(f16x8*)(ldsW + it * 2048 + base) = v;
        }
    }

    const int nG = (N + 15) >> 4;
    for (int g = b0; g < nG; g += GB) {
        // ---------------- gather: this thread's 8 feats of node nk --------
        f16x8 rowv;
        #pragma unroll
        for (int j = 0; j < 8; ++j) rowv[j] = (_Float16)0.f;
        const int idx = g * 16 + nk;
        if (idx < N) {
            const int node_g = order[dbase + (N - 1 - idx)];
            const int node   = node_g - dbase;
            const int start  = offsets[node_g];
            const int cnt    = counts[node_g];
            const float ad   = ad1[(size_t)node * HEADS + hh];
            float den = 0.f;
            float acc[8];
            #pragma unroll
            for (int j = 0; j < 8; ++j) acc[j] = 0.f;
            const int last = cnt - 1;
            for (int i = 0; i < cnt; i += 4) {
                const int i1 = (i + 1 < cnt) ? i + 1 : last;
                const int i2 = (i + 2 < cnt) ? i + 2 : last;
                const int i3 = (i + 3 < cnt) ? i + 3 : last;
                const int s0 = perm[start + i];
                const int s1 = perm[start + i1];
                const int s2 = perm[start + i2];
                const int s3 = perm[start + i3];
                const float a0 = as1[(size_t)s0 * HEADS + hh];
                const float a1 = as1[(size_t)s1 * HEADS + hh];
                const float a2 = as1[(size_t)s2 * HEADS + hh];
                const float a3 = as1[(size_t)s3 * HEADS + hh];
                f16x8 h0 = *(const f16x8*)(h1 + (size_t)s0 * 128 + f0);
                f16x8 hb = *(const f16x8*)(h1 + (size_t)s1 * 128 + f0);
                f16x8 hc = *(const f16x8*)(h1 + (size_t)s2 * 128 + f0);
                f16x8 hd = *(const f16x8*)(h1 + (size_t)s3 * 128 + f0);
                const float e0 = __expf(leaky02(a0 + ad));
                float e1 = __expf(leaky02(a1 + ad));
                float e2 = __expf(leaky02(a2 + ad));
                float e3 = __expf(leaky02(a3 + ad));
                if (i + 1 >= cnt) e1 = 0.f;
                if (i + 2 >= cnt) e2 = 0.f;
                if (i + 3 >= cnt) e3 = 0.f;
                den += (e0 + e1) + (e2 + e3);
                #pragma unroll
                for (int j = 0; j < 8; ++j)
                    acc[j] += e0 * (float)h0[j] + e1 * (float)hb[j]
                            + e2 * (float)hc[j] + e3 * (float)hd[j];
            }
            const float inv = 1.f / (den + 1e-16f);
            #pragma unroll
            for (int j = 0; j < 8; ++j)
                rowv[j] = (_Float16)fmaxf(acc[j] * inv, 0.f);
        }
        *(f16x8*)(ldsA + nk * SAF + f0) = rowv;
        __syncthreads();

        // ---------------- projection: wave computes cols 16w..16w+15 ------
        f32x4 c = (f32x4){0.f, 0.f, 0.f, 0.f};
        const int ab = m * SAF;
        #pragma unroll
        for (int t = 0; t < 4; ++t) {
            f16x8 a  = *(const f16x8*)(ldsA + ab + t * 32 + quad * 8);
            f16x8 bf = *(const f16x8*)(ldsW + ((t * 4 + wave) * 64 + lane) * 8);
            c = __builtin_amdgcn_mfma_f32_16x16x32_f16(a, bf, c, 0, 0, 0);
        }
        const float bias = bb[wave * 16 + m];
        #pragma unroll
        for (int r = 0; r < 4; ++r)
            ldsH[(quad * 4 + r) * SH + wave * 16 + m] = (_Float16)(c[r] + bias);
        __syncthreads();

        // ---------------- layer-2 alpha (wave 0: 16 rows x 4 heads) -------
        if (wave == 0) {
            const int r = lane >> 2;
            const int q = lane & 3;
            const int aidx = g * 16 + r;
            if (aidx < N) {
                const int anode = order[dbase + (N - 1 - aidx)] - dbase;
                float ps = 0.f, pd = 0.f;
                #pragma unroll
                for (int jj = 0; jj < 4; ++jj) {
                    f16x4 v4 = *(const f16x4*)(&ldsH[r * SH + q * 16 + 4 * jj]);
                    float4 s4 = *(const float4*)(sv + q * 16 + 4 * jj);
                    float4 d4 = *(const float4*)(dv + q * 16 + 4 * jj);
                    const float v0 = (float)v4[0], v1 = (float)v4[1],
                                v2 = (float)v4[2], v3 = (float)v4[3];
                    ps += v0 * s4.x + v1 * s4.y + v2 * s4.z + v3 * s4.w;
                    pd += v0 * d4.x + v1 * d4.y + v2 * d4.z + v3 * d4.w;
                }
                as2[(size_t)anode * HEADS + q] = ps;
                ad2[(size_t)anode * HEADS + q] = pd;
            }
        }
        // ---------------- h2 store: wave w -> rows 4w..4w+3 ---------------
        {
            const int lr  = lane & 15;
            const int rq  = lane >> 4;
            const int row = wave * 4 + rq;
            const int sidx = g * 16 + row;
            if (sidx < N) {
                const int snode = order[dbase + (N - 1 - sidx)] - dbase;
                f16x4 v = *(const f16x4*)(&ldsH[row * SH + lr * 4]);
                *(f16x4*)(h2 + (size_t)snode * 64 + lr * 4) = v;
            }
        }
        // no barrier here: next gather only touches ldsA (guarded by the
        // post-MFMA barrier); ldsH readers complete in program order.
    }
}

// ---------------------------------------------------------------------------
// Layer-2 fused per-dst softmax + aggregation.
// ---------------------------------------------------------------------------
template<int F, int D>
__global__ __launch_bounds__(256) void csr_attn_agg_dual(
    const int* __restrict__ order,
    const int* __restrict__ perm, const int* __restrict__ offsets,
    const int* __restrict__ counts,
    const float* __restrict__ asrcP, const float* __restrict__ adstP,
    const _Float16* __restrict__ hP, _Float16* __restrict__ outA,
    const float* __restrict__ asrcA, const float* __restrict__ adstA,
    const _Float16* __restrict__ hA, _Float16* __restrict__ outP,
    int N) {
    constexpr int LPN = F / 8;
    const int gid  = blockIdx.x * 256 + threadIdx.x;
    const int slotF = gid / LPN;
    const int lane  = gid % LPN;
    if (slotF >= 2 * N) return;
    const int slot = 2 * N - 1 - slotF;          // descending degree (LPT)
    const int node_g = order[slot];
    const bool second = node_g >= N;
    const int node = second ? node_g - N : node_g;
    const float* __restrict__ asrc    = second ? asrcA : asrcP;
    const float* __restrict__ adst    = second ? adstA : adstP;
    const _Float16* __restrict__ hsrc = second ? hA : hP;
    _Float16* __restrict__ out        = second ? outP : outA;

    const int start = offsets[node_g];
    const int cnt   = counts[node_g];
    const int f0 = lane * 8;
    const int h  = f0 / D;
    const float ad = adst[(size_t)node * HEADS + h];

    float den = 0.f;
    float acc[8];
    #pragma unroll
    for (int j = 0; j < 8; ++j) acc[j] = 0.f;
    const int last = cnt - 1;
    for (int i = 0; i < cnt; i += 4) {
        const int i1 = (i + 1 < cnt) ? i + 1 : last;
        const int i2 = (i + 2 < cnt) ? i + 2 : last;
        const int i3 = (i + 3 < cnt) ? i + 3 : last;
        const int s0 = perm[start + i];
        const int s1 = perm[start + i1];
        const int s2 = perm[start + i2];
        const int s3 = perm[start + i3];
        const float a0 = asrc[(size_t)s0 * HEADS + h];
        const float a1 = asrc[(size_t)s1 * HEADS + h];
        const float a2 = asrc[(size_t)s2 * HEADS + h];
        const float a3 = asrc[(size_t)s3 * HEADS + h];
        f16x8 h0 = *(const f16x8*)(hsrc + (size_t)s0 * F + f0);
        f16x8 h1 = *(const f16x8*)(hsrc + (size_t)s1 * F + f0);
        f16x8 h2 = *(const f16x8*)(hsrc + (size_t)s2 * F + f0);
        f16x8 h3 = *(const f16x8*)(hsrc + (size_t)s3 * F + f0);
        const float e0 = __expf(leaky02(a0 + ad));
        float e1 = __expf(leaky02(a1 + ad));
        float e2 = __expf(leaky02(a2 + ad));
        float e3 = __expf(leaky02(a3 + ad));
        if (i + 1 >= cnt) e1 = 0.f;
        if (i + 2 >= cnt) e2 = 0.f;
        if (i + 3 >= cnt) e3 = 0.f;
        den += (e0 + e1) + (e2 + e3);
        #pragma unroll
        for (int j = 0; j < 8; ++j)
            acc[j] += e0 * (float)h0[j] + e1 * (float)h1[j]
                    + e2 * (float)h2[j] + e3 * (float)h3[j];
    }
    const float inv = 1.f / (den + 1e-16f);
    f16x8 o;
    #pragma unroll
    for (int j = 0; j < 8; ++j)
        o[j] = (_Float16)fmaxf(acc[j] * inv, 0.f);
    *(f16x8*)(out + (size_t)node * F + f0) = o;
}

// ---------------------------------------------------------------------------
// Final: out[l] = dot(zp[eli0[l]], za[eli1[l]]), 64 fp16 feats -> fp32.
// ---------------------------------------------------------------------------
__global__ __launch_bounds__(256) void edge_dot(
    const int* __restrict__ eli, const _Float16* __restrict__ zp,
    const _Float16* __restrict__ za, float* __restrict__ out, int L) {
    constexpr int LPE = 8;
    const int gid  = blockIdx.x * blockDim.x + threadIdx.x;
    const int e    = gid / LPE;
    const int lane = gid % LPE;
    if (e >= L) return;
    const int p = eli[e], a = eli[(size_t)L + e];
    f16x8 pv = *(const f16x8*)(zp + (size_t)p * 64 + lane * 8);
    f16x8 av = *(const f16x8*)(za + (size_t)a * 64 + lane * 8);
    float s = 0.f;
    #pragma unroll
    for (int j = 0; j < 8; ++j) s += (float)pv[j] * (float)av[j];
    #pragma unroll
    for (int off = 4; off > 0; off >>= 1) s += __shfl_xor(s, off);
    if (lane == 0) out[e] = s;
}

// ---------------------------------------------------------------------------
static inline int cdiv(long long a, long long b) { return (int)((a + b - 1) / b); }

extern "C" void kernel_launch(void* const* d_in, const int* in_sizes, int n_in,
                              void* d_out, int out_size, void* d_ws, size_t ws_size,
                              hipStream_t stream) {
    const float* x_p  = (const float*)d_in[0];
    const float* x_a  = (const float*)d_in[1];
    const int* ei_pa  = (const int*)d_in[2];
    const int* ei_ap  = (const int*)d_in[3];
    const int* eli    = (const int*)d_in[4];
    const float* p1W = (const float*)d_in[5];
    const float* p1b = (const float*)d_in[6];
    const float* a1W = (const float*)d_in[7];
    const float* a1b = (const float*)d_in[8];
    const float* s1pa = (const float*)d_in[9];
    const float* d1pa = (const float*)d_in[10];
    const float* s1ap = (const float*)d_in[11];
    const float* d1ap = (const float*)d_in[12];
    // 13..15: k1W, k1b, q1 — dead (single-metapath group == identity)
    const float* p2W = (const float*)d_in[16];
    const float* p2b = (const float*)d_in[17];
    const float* a2W = (const float*)d_in[18];
    const float* a2b = (const float*)d_in[19];
    const float* s2pa = (const float*)d_in[20];
    const float* d2pa = (const float*)d_in[21];
    const float* s2ap = (const float*)d_in[22];
    const float* d2ap = (const float*)d_in[23];
    // 24..26: k2W, k2b, q2 — dead

    const int NP = in_sizes[0] / 128;
    const int E  = in_sizes[2] / 2;
    const int L  = in_sizes[4] / 2;
    const int N  = NP;  // NP == NA

    // ---- workspace layout ----
    char* ws = (char*)d_ws;
    size_t off = 0;
    auto alloc = [&](size_t bytes) -> char* {
        char* p = ws + off;
        off += (bytes + 255) & ~(size_t)255;
        return p;
    };
    _Float16* h_p1   = (_Float16*)alloc((size_t)N * 128 * 2);
    _Float16* h_a1   = (_Float16*)alloc((size_t)N * 128 * 2);
    _Float16* h_p2   = (_Float16*)alloc((size_t)N * 64 * 2);
    _Float16* h_a2   = (_Float16*)alloc((size_t)N * 64 * 2);
    _Float16* out_p2 = (_Float16*)alloc((size_t)N * 64 * 2);
    _Float16* out_a2 = (_Float16*)alloc((size_t)N * 64 * 2);
    float* asrc_pa = (float*)alloc((size_t)N * HEADS * 4);
    float* adst_pa = (float*)alloc((size_t)N * HEADS * 4);
    float* asrc_ap = (float*)alloc((size_t)N * HEADS * 4);
    float* adst_ap = (float*)alloc((size_t)N * HEADS * 4);
    float* as2_pa  = (float*)alloc((size_t)N * HEADS * 4);
    float* ad2_pa  = (float*)alloc((size_t)N * HEADS * 4);
    float* as2_ap  = (float*)alloc((size_t)N * HEADS * 4);
    float* ad2_ap  = (float*)alloc((size_t)N * HEADS * 4);
    _Float16* Wf1p = (_Float16*)alloc(16384 * 2);
    _Float16* Wf1a = (_Float16*)alloc(16384 * 2);
    _Float16* Wf2p = (_Float16*)alloc(8192 * 2);
    _Float16* Wf2a = (_Float16*)alloc(8192 * 2);
    // cnt2 / cursor2 / bhist are contiguous: one memset covers them
    int* cnt2    = (int*)alloc((size_t)2 * N * 4);
    int* cursor2 = (int*)alloc((size_t)2 * N * 4);
    int* bhist   = (int*)alloc(512);            // 128 ints
    int* off2    = (int*)alloc((size_t)2 * N * 4);
    int* perm2   = (int*)alloc((size_t)2 * E * 4);
    int* order2  = (int*)alloc((size_t)2 * N * 4);
    int* bsum    = (int*)alloc(256 * 4);

    const int* src_pa = ei_pa;       // papers
    const int* dst_pa = ei_pa + E;   // authors
    const int* src_ap = ei_ap;       // authors
    const int* dst_ap = ei_ap + E;   // papers

    const int N2 = 2 * N;
    const int nbScan = cdiv(N2, 1024);

    // ================= prep + CSR build + direction-major degree sort =====
    prep_w4<<<cdiv(49152, 256), 256, 0, stream>>>(p1W, Wf1p, a1W, Wf1a, p2W, Wf2p, a2W, Wf2a);
    hipMemsetAsync(cnt2, 0, ((size_t)4 * N + 128) * 4, stream);  // cnt2+cursor2+bhist
    hist_dual<<<cdiv((long long)2 * E, 256), 256, 0, stream>>>(dst_pa, dst_ap, cnt2, N, E);
    scan_blk<<<nbScan, 256, 0, stream>>>(cnt2, off2, bsum, bhist, N2);
    scan_sums2<<<2, 256, 0, stream>>>(bsum, nbScan, bhist);
    finalize_degscatter<<<nbScan, 256, 0, stream>>>(off2, bsum, cnt2, bhist, order2, N2);
    scatter_dual<<<cdiv((long long)2 * E, 256), 256, 0, stream>>>(
        src_pa, dst_pa, src_ap, dst_ap, off2, cursor2, perm2, N, E);

    const int nbs1 = cdiv(N, 64) * 2;   // 64-row tiles x 2 col-splits (M=128)

    // ================= Layer 1 GEMM =================
    gemm_mfma_dual<128, false><<<2 * nbs1, 256, 0, stream>>>(
        x_p, Wf1p, p1b, h_p1, s1pa, d1ap, asrc_pa, adst_ap,
        x_a, Wf1a, a1b, h_a1, s1ap, d1pa, asrc_ap, adst_pa, N, nbs1);

    // ================= Fused agg1 + layer-2 projection =================
    // dir0 (author dst): gather h_p1 w/ (asrc_pa, adst_pa); proj a2W -> h_a2
    // dir1 (paper dst):  gather h_a1 w/ (asrc_ap, adst_ap); proj p2W -> h_p2
    const int nG = cdiv(N, 16);
    const int GB = cdiv(nG, 10);        // r7-best: ~10 groups/block, 625 blocks
    agg_proj_dual<<<2 * GB, 256, 0, stream>>>(
        order2, perm2, off2, cnt2,
        asrc_pa, adst_pa, h_p1, Wf2a, a2b, h_a2, s2ap, d2pa, as2_ap, ad2_pa,
        asrc_ap, adst_ap, h_a1, Wf2p, p2b, h_p2, s2pa, d2ap, as2_pa, ad2_ap,
        N, GB);

    // ================= Layer 2 aggregation =================
    csr_attn_agg_dual<64, 16><<<cdiv((long long)N2 * 8, 256), 256, 0, stream>>>(
        order2, perm2, off2, cnt2,
        as2_pa, ad2_pa, h_p2, out_a2,
        as2_ap, ad2_ap, h_a2, out_p2, N);

    // ================= Final dot =================
    edge_dot<<<cdiv((long long)L * 8, 256), 256, 0, stream>>>(
        eli, out_p2, out_a2, (float*)d_out, L);
}